// Round 2
// baseline (156.148 us; speedup 1.0000x reference)
//
#include <hip/hip_runtime.h>
#include <math.h>

#define BB 4
#define TT 2048
#define DM 768
#define HD 64
#define NROW (BB*TT)   // 8192

// ---------------- Fused QKV projection ----------------
// grid 256 blocks x 256 threads; each block: 32 rows x (3x64) cols
__global__ __launch_bounds__(256) void qkv_proj_kernel(
    const float* __restrict__ x,
    const float* __restrict__ Wq, const float* __restrict__ bq,
    const float* __restrict__ Wk, const float* __restrict__ bk,
    const float* __restrict__ Wv, const float* __restrict__ bv,
    float* __restrict__ qo, float* __restrict__ ko, float* __restrict__ vo)
{
    __shared__ float xs[32][68];
    __shared__ float wt[64][196];
    const int tid = threadIdx.x;
    const int rg = tid >> 4;      // 0..15 -> rows 2rg, 2rg+1
    const int cg = tid & 15;      // 0..15 -> cols 4cg..4cg+3 of each matrix
    const int row0 = blockIdx.x * 32;

    float acc[2][3][4];
    #pragma unroll
    for (int i = 0; i < 2; ++i)
        #pragma unroll
        for (int m = 0; m < 3; ++m)
            #pragma unroll
            for (int e = 0; e < 4; ++e) acc[i][m][e] = 0.f;

    for (int kb = 0; kb < DM/64; ++kb) {
        __syncthreads();
        // stage x tile: 32 x 64
        #pragma unroll
        for (int p = 0; p < 2; ++p) {
            int f4 = tid + 256*p;
            int r = f4 >> 4;
            int c = (f4 & 15) << 2;
            float4 vv = *(const float4*)(x + (size_t)(row0 + r)*DM + kb*64 + c);
            *(float4*)(&xs[r][c]) = vv;
        }
        // stage W tile: 64 x 192 (q|k|v)
        #pragma unroll
        for (int p = 0; p < 12; ++p) {
            int f4 = tid + 256*p;
            int c4 = f4 % 48;            // float4-column 0..47
            int r  = f4 / 48;            // 0..63
            int mat = c4 >> 4;           // 0..2
            int cm  = (c4 & 15) << 2;    // col within one matrix
            const float* Wp = (mat == 0) ? Wq : ((mat == 1) ? Wk : Wv);
            float4 vv = *(const float4*)(Wp + (size_t)(kb*64 + r)*HD + cm);
            *(float4*)(&wt[r][c4*4]) = vv;
        }
        __syncthreads();
        // compute: 64 kk per chunk
        #pragma unroll
        for (int ks = 0; ks < 16; ++ks) {
            float4 a0 = *(const float4*)(&xs[2*rg+0][ks*4]);
            float4 a1 = *(const float4*)(&xs[2*rg+1][ks*4]);
            #pragma unroll
            for (int kk = 0; kk < 4; ++kk) {
                float av0 = ((const float*)&a0)[kk];
                float av1 = ((const float*)&a1)[kk];
                #pragma unroll
                for (int m = 0; m < 3; ++m) {
                    float4 b = *(const float4*)(&wt[ks*4+kk][4*cg + 64*m]);
                    #pragma unroll
                    for (int e = 0; e < 4; ++e) {
                        acc[0][m][e] = fmaf(av0, ((const float*)&b)[e], acc[0][m][e]);
                        acc[1][m][e] = fmaf(av1, ((const float*)&b)[e], acc[1][m][e]);
                    }
                }
            }
        }
    }
    // epilogue: bias + store (float4, coalesced)
    #pragma unroll
    for (int m = 0; m < 3; ++m) {
        const float* bp = (m == 0) ? bq : ((m == 1) ? bk : bv);
        float* op = (m == 0) ? qo : ((m == 1) ? ko : vo);
        float4 bias = *(const float4*)(bp + 4*cg);
        #pragma unroll
        for (int i = 0; i < 2; ++i) {
            float4 r;
            r.x = acc[i][m][0] + bias.x;
            r.y = acc[i][m][1] + bias.y;
            r.z = acc[i][m][2] + bias.z;
            r.w = acc[i][m][3] + bias.w;
            *(float4*)(op + (size_t)(row0 + 2*rg + i)*HD + 4*cg) = r;
        }
    }
}

// ---------------- Flash attention (causal, fp32, pair-balanced) ----------------
// grid (64, 4) x 256 threads. Block i handles q-rows [16i,16i+16) (phase 0)
// and [2032-16i, 2048-16i) (phase 1): constant 2064 keys of work per block.
__global__ __launch_bounds__(256) void attn_kernel(
    const float* __restrict__ q, const float* __restrict__ k,
    const float* __restrict__ v, float* __restrict__ out)
{
    __shared__ float qs[16][68];
    __shared__ float ks[64][68];
    __shared__ float vs[64][68];
    __shared__ float ps[16][68];

    const int tid = threadIdx.x;
    const int rg = tid >> 4;   // 0..15: this thread's q-row within tile
    const int cg = tid & 15;   // 0..15: column group
    const int ib = blockIdx.x; // 0..63
    const int b  = blockIdx.y;

    const float* qb  = q + (size_t)b*TT*HD;
    const float* kbp = k + (size_t)b*TT*HD;
    const float* vbp = v + (size_t)b*TT*HD;

    #pragma unroll
    for (int phase = 0; phase < 2; ++phase) {
        const int row0 = (phase == 0) ? 16*ib : (TT - 16 - 16*ib);
        const int qr   = row0 + rg;

        __syncthreads();   // prev phase done with qs/ps before re-staging
        // stage q tile (16x64), scaled by 1/sqrt(64)=0.125; one float4/thread
        {
            int r = tid >> 4;
            int c = (tid & 15) << 2;
            float4 vv = *(const float4*)(qb + (size_t)(row0 + r)*HD + c);
            vv.x *= 0.125f; vv.y *= 0.125f; vv.z *= 0.125f; vv.w *= 0.125f;
            *(float4*)(&qs[r][c]) = vv;
        }

        float o[4] = {0.f, 0.f, 0.f, 0.f};
        float mrow = -INFINITY, lrow = 0.f;
        const int nkt = (row0 + 15)/64 + 1;

        for (int kt = 0; kt < nkt; ++kt) {
            __syncthreads();   // prev PV reads done before overwriting ks/vs
            #pragma unroll
            for (int p = 0; p < 4; ++p) {
                int f4 = tid + 256*p;
                int r = f4 >> 4;
                int c = (f4 & 15) << 2;
                *(float4*)(&ks[r][c]) = *(const float4*)(kbp + (size_t)(kt*64 + r)*HD + c);
                *(float4*)(&vs[r][c]) = *(const float4*)(vbp + (size_t)(kt*64 + r)*HD + c);
            }
            __syncthreads();

            // S[qr][cg+16m] = (q*scale) . k  ; strided cols -> 2-way (free) ks reads
            float s[4] = {0.f, 0.f, 0.f, 0.f};
            #pragma unroll
            for (int hh = 0; hh < 16; ++hh) {
                float4 a0 = *(const float4*)(&qs[rg][hh*4]);
                #pragma unroll
                for (int m = 0; m < 4; ++m) {
                    float4 bv4 = *(const float4*)(&ks[cg+16*m][hh*4]);
                    #pragma unroll
                    for (int e = 0; e < 4; ++e)
                        s[m] = fmaf(((const float*)&a0)[e], ((const float*)&bv4)[e], s[m]);
                }
            }
            // causal mask (only near-diagonal tiles)
            if (kt*64 + 63 > qr) {
                #pragma unroll
                for (int m = 0; m < 4; ++m) {
                    int kc = kt*64 + cg + 16*m;
                    if (kc > qr) s[m] = -INFINITY;
                }
            }
            // online softmax: 16 consecutive lanes own one row
            float mt = fmaxf(fmaxf(s[0], s[1]), fmaxf(s[2], s[3]));
            mt = fmaxf(mt, __shfl_xor(mt, 1));
            mt = fmaxf(mt, __shfl_xor(mt, 2));
            mt = fmaxf(mt, __shfl_xor(mt, 4));
            mt = fmaxf(mt, __shfl_xor(mt, 8));
            float mnew = fmaxf(mrow, mt);
            float alpha = __expf(mrow - mnew);
            mrow = mnew;
            float psum = 0.f;
            #pragma unroll
            for (int m = 0; m < 4; ++m) {
                float pv = __expf(s[m] - mnew);
                s[m] = pv;
                psum += pv;
            }
            psum += __shfl_xor(psum, 1);
            psum += __shfl_xor(psum, 2);
            psum += __shfl_xor(psum, 4);
            psum += __shfl_xor(psum, 8);
            lrow = lrow*alpha + psum;
            #pragma unroll
            for (int e = 0; e < 4; ++e) o[e] *= alpha;
            #pragma unroll
            for (int m = 0; m < 4; ++m) ps[rg][cg+16*m] = s[m];
            __syncthreads();

            // PV: o[e] += sum_j ps[rg][j] * vs[j][4cg+e]
            #pragma unroll
            for (int jj = 0; jj < 16; ++jj) {
                float4 p0 = *(const float4*)(&ps[rg][jj*4]);
                #pragma unroll
                for (int u = 0; u < 4; ++u) {
                    float4 vv = *(const float4*)(&vs[jj*4+u][4*cg]);
                    #pragma unroll
                    for (int e = 0; e < 4; ++e)
                        o[e] = fmaf(((const float*)&p0)[u], ((const float*)&vv)[e], o[e]);
                }
            }
        }
        // epilogue for this phase
        {
            float inv = 1.f / lrow;
            float4 r;
            r.x = o[0]*inv; r.y = o[1]*inv; r.z = o[2]*inv; r.w = o[3]*inv;
            *(float4*)(out + ((size_t)b*TT + qr)*HD + 4*cg) = r;
        }
    }
}

extern "C" void kernel_launch(void* const* d_in, const int* in_sizes, int n_in,
                              void* d_out, int out_size, void* d_ws, size_t ws_size,
                              hipStream_t stream) {
    const float* x  = (const float*)d_in[0];
    const float* Wq = (const float*)d_in[1];
    const float* bq = (const float*)d_in[2];
    const float* Wk = (const float*)d_in[3];
    const float* bk = (const float*)d_in[4];
    const float* Wv = (const float*)d_in[5];
    const float* bv = (const float*)d_in[6];
    float* out = (float*)d_out;

    float* q = (float*)d_ws;
    float* k = q + (size_t)NROW*HD;
    float* v = k + (size_t)NROW*HD;

    qkv_proj_kernel<<<NROW/32, 256, 0, stream>>>(x, Wq, bq, Wk, bk, Wv, bv, q, k, v);
    attn_kernel<<<dim3(TT/32, BB), 256, 0, stream>>>(q, k, v, out);
}

// Round 3
// 72.071 us; speedup vs baseline: 2.1666x; 2.1666x over previous
//
#include <hip/hip_runtime.h>
#include <math.h>

#define BB 4
#define TT 2048
#define DM 768
#define HD 64
#define NROW (BB*TT)   // 8192

typedef __attribute__((ext_vector_type(8))) short bf16x8;
typedef __attribute__((ext_vector_type(4))) float f32x4;

__device__ __forceinline__ unsigned short f2bf(float f) {
    unsigned int u = __float_as_uint(f);
    u += 0x7FFFu + ((u >> 16) & 1u);   // RNE
    return (unsigned short)(u >> 16);
}

// ---------------- Fused QKV projection (fp32 compute, bf16 outputs) ----------------
// grid 256 blocks x 256 threads; each block: 32 rows x (3x64) cols
__global__ __launch_bounds__(256) void qkv_proj_kernel(
    const float* __restrict__ x,
    const float* __restrict__ Wq, const float* __restrict__ bq,
    const float* __restrict__ Wk, const float* __restrict__ bk,
    const float* __restrict__ Wv, const float* __restrict__ bv,
    unsigned short* __restrict__ qo, unsigned short* __restrict__ ko,
    unsigned short* __restrict__ vT)
{
    __shared__ float xs[32][68];
    __shared__ float wt[64][196];
    const int tid = threadIdx.x;
    const int rg = tid >> 4;
    const int cg = tid & 15;
    const int row0 = blockIdx.x * 32;

    float acc[2][3][4];
    #pragma unroll
    for (int i = 0; i < 2; ++i)
        #pragma unroll
        for (int m = 0; m < 3; ++m)
            #pragma unroll
            for (int e = 0; e < 4; ++e) acc[i][m][e] = 0.f;

    for (int kb = 0; kb < DM/64; ++kb) {
        __syncthreads();
        #pragma unroll
        for (int p = 0; p < 2; ++p) {
            int f4 = tid + 256*p;
            int r = f4 >> 4;
            int c = (f4 & 15) << 2;
            *(float4*)(&xs[r][c]) = *(const float4*)(x + (size_t)(row0 + r)*DM + kb*64 + c);
        }
        #pragma unroll
        for (int p = 0; p < 12; ++p) {
            int f4 = tid + 256*p;
            int c4 = f4 % 48;
            int r  = f4 / 48;
            int mat = c4 >> 4;
            int cm  = (c4 & 15) << 2;
            const float* Wp = (mat == 0) ? Wq : ((mat == 1) ? Wk : Wv);
            *(float4*)(&wt[r][c4*4]) = *(const float4*)(Wp + (size_t)(kb*64 + r)*HD + cm);
        }
        __syncthreads();
        #pragma unroll
        for (int ks = 0; ks < 16; ++ks) {
            float4 a0 = *(const float4*)(&xs[2*rg+0][ks*4]);
            float4 a1 = *(const float4*)(&xs[2*rg+1][ks*4]);
            #pragma unroll
            for (int kk = 0; kk < 4; ++kk) {
                float av0 = ((const float*)&a0)[kk];
                float av1 = ((const float*)&a1)[kk];
                #pragma unroll
                for (int m = 0; m < 3; ++m) {
                    float4 b = *(const float4*)(&wt[ks*4+kk][4*cg + 64*m]);
                    #pragma unroll
                    for (int e = 0; e < 4; ++e) {
                        acc[0][m][e] = fmaf(av0, ((const float*)&b)[e], acc[0][m][e]);
                        acc[1][m][e] = fmaf(av1, ((const float*)&b)[e], acc[1][m][e]);
                    }
                }
            }
        }
    }
    const float4 biq = *(const float4*)(bq + 4*cg);
    const float4 bik = *(const float4*)(bk + 4*cg);
    const float4 biv = *(const float4*)(bv + 4*cg);
    #pragma unroll
    for (int i = 0; i < 2; ++i) {
        int row = row0 + 2*rg + i;
        ushort4 qv, kv;
        qv.x = f2bf((acc[i][0][0] + biq.x) * 0.125f);
        qv.y = f2bf((acc[i][0][1] + biq.y) * 0.125f);
        qv.z = f2bf((acc[i][0][2] + biq.z) * 0.125f);
        qv.w = f2bf((acc[i][0][3] + biq.w) * 0.125f);
        kv.x = f2bf(acc[i][1][0] + bik.x);
        kv.y = f2bf(acc[i][1][1] + bik.y);
        kv.z = f2bf(acc[i][1][2] + bik.z);
        kv.w = f2bf(acc[i][1][3] + bik.w);
        *(ushort4*)(qo + (size_t)row*HD + 4*cg) = qv;
        *(ushort4*)(ko + (size_t)row*HD + 4*cg) = kv;
        int b = row >> 11, t = row & 2047;
        #pragma unroll
        for (int e = 0; e < 4; ++e)
            vT[((size_t)b*HD + 4*cg + e)*TT + t] = f2bf(acc[i][2][e] + ((const float*)&biv)[e]);
    }
}

// ---------------- Flash attention: bf16 MFMA, in-block 4-way key split ----------------
// grid 512 blocks (b = bx&3, qt = 127-(bx>>2), big tiles dispatched first) x 256 thr.
// Each wave: 16 q-rows x (1/4 of key range). LDS combine of (O,m,l) at the end.
__global__ __launch_bounds__(256) void attn_mfma_kernel(
    const unsigned short* __restrict__ qb_, const unsigned short* __restrict__ kb_,
    const unsigned short* __restrict__ vt_, float* __restrict__ out)
{
    __shared__ unsigned short plds[4][16][40];  // per-wave P transpose scratch
    __shared__ float olds[4][16][66];           // per-wave O partials
    __shared__ float mlds[4][16][2];            // per-wave (m,l)

    const int tid  = threadIdx.x;
    const int wv   = tid >> 6;
    const int lane = tid & 63;
    const int q15  = lane & 15;
    const int g    = lane >> 4;

    const int bx = blockIdx.x;
    const int b  = bx & 3;
    const int qt = (TT/16 - 1) - (bx >> 2);
    const int qbase = qt * 16;
    const int nk = qbase + 16;                  // causal key count for this tile

    const unsigned short* qp = qb_ + (size_t)b*TT*HD;
    const unsigned short* kp = kb_ + (size_t)b*TT*HD;
    const unsigned short* vp = vt_ + (size_t)b*HD*TT;

    // Q fragments (B operand of S^T = K x Q^T): lane holds Q[q15][32c+8g+j]
    bf16x8 qf[2];
    #pragma unroll
    for (int c = 0; c < 2; ++c)
        qf[c] = *(const bf16x8*)(qp + (size_t)(qbase + q15)*HD + 32*c + 8*g);

    f32x4 accv[4];
    #pragma unroll
    for (int h = 0; h < 4; ++h) accv[h] = (f32x4){0.f, 0.f, 0.f, 0.f};
    float m = -INFINITY, l = 0.f;

    const int ck = ((nk + 127) >> 7) << 5;      // per-wave chunk, multiple of 32
    const int kstart = wv * ck;
    const int kend = min(kstart + ck, nk);

    for (int k0 = kstart; k0 < kend; k0 += 32) {
        // V^T B-fragments: lane holds V[k0+8g+j][16h+q15]
        bf16x8 vf[4];
        #pragma unroll
        for (int h = 0; h < 4; ++h)
            vf[h] = *(const bf16x8*)(vp + (size_t)(16*h + q15)*TT + k0 + 8*g);
        // K A-fragments: lane holds K[k0+16t+q15][32c+8g+j]
        bf16x8 kf[2][2];
        #pragma unroll
        for (int t = 0; t < 2; ++t)
            #pragma unroll
            for (int c = 0; c < 2; ++c)
                kf[t][c] = *(const bf16x8*)(kp + (size_t)(k0 + 16*t + q15)*HD + 32*c + 8*g);

        // S^T[key][q]: D row = key = 16t+4g+r, col = q = q15 (q pre-scaled by 1/8)
        f32x4 st[2];
        #pragma unroll
        for (int t = 0; t < 2; ++t) {
            f32x4 z = {0.f, 0.f, 0.f, 0.f};
            st[t] = __builtin_amdgcn_mfma_f32_16x16x32_bf16(kf[t][0], qf[0], z, 0, 0, 0);
            st[t] = __builtin_amdgcn_mfma_f32_16x16x32_bf16(kf[t][1], qf[1], st[t], 0, 0, 0);
        }
        // causal mask (covers the partial tail tile too: keys >= nk are > all q)
        if (k0 + 31 > qbase) {
            int qabs = qbase + q15;
            #pragma unroll
            for (int t = 0; t < 2; ++t)
                #pragma unroll
                for (int r = 0; r < 4; ++r)
                    if (k0 + 16*t + 4*g + r > qabs) st[t][r] = -INFINITY;
        }
        // online softmax: lane owns q=q15; reduce 8 regs + groups via xor16/32
        float pmax = st[0][0];
        #pragma unroll
        for (int t = 0; t < 2; ++t)
            #pragma unroll
            for (int r = 0; r < 4; ++r) pmax = fmaxf(pmax, st[t][r]);
        pmax = fmaxf(pmax, __shfl_xor(pmax, 16));
        pmax = fmaxf(pmax, __shfl_xor(pmax, 32));
        float mnew = fmaxf(m, pmax);
        float mc = fmaxf(mnew, -1e30f);         // NaN-proof exponent base
        float alpha = __expf(m - mc);
        float p[2][4];
        float psum = 0.f;
        #pragma unroll
        for (int t = 0; t < 2; ++t)
            #pragma unroll
            for (int r = 0; r < 4; ++r) {
                p[t][r] = __expf(st[t][r] - mc);
                psum += p[t][r];
            }
        psum += __shfl_xor(psum, 16);
        psum += __shfl_xor(psum, 32);
        l = l * alpha + psum;
        m = mnew;
        // rescale O: lane's O rows are 4g+r -> fetch their alpha from lane 4g+r
        float av[4];
        #pragma unroll
        for (int r = 0; r < 4; ++r) av[r] = __shfl(alpha, 4*g + r);
        #pragma unroll
        for (int h = 0; h < 4; ++h)
            #pragma unroll
            for (int r = 0; r < 4; ++r) accv[h][r] *= av[r];
        // P -> bf16, transpose to MFMA-A layout via per-wave LDS
        #pragma unroll
        for (int t = 0; t < 2; ++t) {
            ushort4 pk;
            pk.x = f2bf(p[t][0]); pk.y = f2bf(p[t][1]);
            pk.z = f2bf(p[t][2]); pk.w = f2bf(p[t][3]);
            *(ushort4*)&plds[wv][q15][16*t + 4*g] = pk;
        }
        bf16x8 pa = *(const bf16x8*)&plds[wv][q15][8*g];
        // PV: O[q][hd] += P[q][key] * V[key][hd]
        #pragma unroll
        for (int h = 0; h < 4; ++h)
            accv[h] = __builtin_amdgcn_mfma_f32_16x16x32_bf16(pa, vf[h], accv[h], 0, 0, 0);
    }

    // publish per-wave partials
    #pragma unroll
    for (int h = 0; h < 4; ++h)
        #pragma unroll
        for (int r = 0; r < 4; ++r)
            olds[wv][4*g + r][16*h + q15] = accv[h][r];
    if (g == 0) { mlds[wv][q15][0] = m; mlds[wv][q15][1] = l; }
    __syncthreads();

    // combine 4 wave-partials: thread (qq, c4)
    {
        int qq = tid >> 4;
        int c4 = (tid & 15) << 2;
        float mw[4], lw[4];
        #pragma unroll
        for (int w = 0; w < 4; ++w) { mw[w] = mlds[w][qq][0]; lw[w] = mlds[w][qq][1]; }
        float M = fmaxf(fmaxf(mw[0], mw[1]), fmaxf(mw[2], mw[3]));
        float Mc = fmaxf(M, -1e30f);
        float ww[4], ltot = 0.f;
        #pragma unroll
        for (int w = 0; w < 4; ++w) { ww[w] = __expf(mw[w] - Mc); ltot += ww[w]*lw[w]; }
        float invl = 1.f / ltot;
        float4 o;
        #pragma unroll
        for (int e = 0; e < 4; ++e) {
            float s = 0.f;
            #pragma unroll
            for (int w = 0; w < 4; ++w) s += ww[w] * olds[w][qq][c4 + e];
            ((float*)&o)[e] = s * invl;
        }
        *(float4*)(out + ((size_t)b*TT + qbase + qq)*HD + c4) = o;
    }
}

extern "C" void kernel_launch(void* const* d_in, const int* in_sizes, int n_in,
                              void* d_out, int out_size, void* d_ws, size_t ws_size,
                              hipStream_t stream) {
    const float* x  = (const float*)d_in[0];
    const float* Wq = (const float*)d_in[1];
    const float* bq = (const float*)d_in[2];
    const float* Wk = (const float*)d_in[3];
    const float* bk = (const float*)d_in[4];
    const float* Wv = (const float*)d_in[5];
    const float* bv = (const float*)d_in[6];
    float* out = (float*)d_out;

    unsigned short* qbf = (unsigned short*)d_ws;
    unsigned short* kbf = qbf + (size_t)NROW*HD;
    unsigned short* vT  = kbf + (size_t)NROW*HD;

    qkv_proj_kernel<<<NROW/32, 256, 0, stream>>>(x, Wq, bq, Wk, bk, Wv, bv, qbf, kbf, vT);
    attn_mfma_kernel<<<dim3(TT/16 * BB), 256, 0, stream>>>(qbf, kbf, vT, out);
}

// Round 4
// 68.210 us; speedup vs baseline: 2.2892x; 1.0566x over previous
//
#include <hip/hip_runtime.h>
#include <math.h>

#define BB 4
#define TT 2048
#define DM 768
#define HD 64
#define NROW (BB*TT)   // 8192
#define WFRAG_HALF ((size_t)12*24*512)   // elems per part

typedef __attribute__((ext_vector_type(8))) short bf16x8;
typedef __attribute__((ext_vector_type(4))) float f32x4;

__device__ __forceinline__ unsigned short f2bf(float f) {
    unsigned int u = __float_as_uint(f);
    u += 0x7FFFu + ((u >> 16) & 1u);   // RNE
    return (unsigned short)(u >> 16);
}
__device__ __forceinline__ float bf2f(unsigned short h) {
    return __uint_as_float(((unsigned int)h) << 16);
}

// -------- W -> MFMA-fragment-ordered bf16 hi/lo  --------
// Wfrag[part][nt(12)][kc(24)][lane(64)][j(8)]; nt = m*4+ntm, col=16*ntm+(lane&15),
// k = 32*kc + 8*(lane>>4) + j. q-scale (0.125) folded into m=0.
__global__ __launch_bounds__(256) void wconv_kernel(
    const float* __restrict__ Wq, const float* __restrict__ Wk,
    const float* __restrict__ Wv, unsigned short* __restrict__ wfrag)
{
    const int blk = blockIdx.x;        // 0..287 = nt*24 + kc
    const int nt = blk / 24;
    const int kc = blk % 24;
    const int m = nt >> 2, ntm = nt & 3;
    const float* Wm = (m == 0) ? Wq : ((m == 1) ? Wk : Wv);
    const float sc = (m == 0) ? 0.125f : 1.0f;
    const int tid = threadIdx.x;
    const int q15 = tid & 15;
    #pragma unroll
    for (int p = 0; p < 2; ++p) {
        int gj = (tid >> 4) + 16*p;    // 0..31
        int g = gj >> 3, j = gj & 7;
        int krow = 32*kc + 8*g + j;
        int col = 16*ntm + q15;
        float w = Wm[(size_t)krow*HD + col] * sc;
        unsigned short hi = f2bf(w);
        unsigned short lo = f2bf(w - bf2f(hi));
        size_t base = ((size_t)nt*24 + kc)*512 + (size_t)(g*16 + q15)*8 + j;
        wfrag[base] = hi;
        wfrag[WFRAG_HALF + base] = lo;
    }
}

// -------- QKV projection via MFMA (x split hi/lo for accuracy) --------
// grid 256 x 256thr; block: 32 rows x 192 cols; wave w: col-tiles nt=3w..3w+2.
__global__ __launch_bounds__(256) void proj_mfma_kernel(
    const float* __restrict__ x, const unsigned short* __restrict__ wfrag,
    const float* __restrict__ bq, const float* __restrict__ bk,
    const float* __restrict__ bv,
    unsigned short* __restrict__ qo, unsigned short* __restrict__ ko,
    unsigned short* __restrict__ vT)
{
    __shared__ unsigned short xsh[2][32][40];   // [hi/lo][row][k], 80B stride (2-way max)
    const int tid  = threadIdx.x;
    const int wv   = tid >> 6;
    const int lane = tid & 63;
    const int q15  = lane & 15;
    const int g    = lane >> 4;
    const int row0 = blockIdx.x * 32;

    f32x4 acc[2][3];
    #pragma unroll
    for (int mt = 0; mt < 2; ++mt)
        #pragma unroll
        for (int i = 0; i < 3; ++i) acc[mt][i] = (f32x4){0.f, 0.f, 0.f, 0.f};

    const int srow = tid >> 3;         // 0..31
    const int sf4  = (tid & 7) * 4;    // 0..28

    for (int kc = 0; kc < 24; ++kc) {
        __syncthreads();               // prev chunk's reads done
        float4 xv = *(const float4*)(x + (size_t)(row0 + srow)*DM + 32*kc + sf4);
        ushort4 xh, xl;
        {
            float f[4] = {xv.x, xv.y, xv.z, xv.w};
            unsigned short h[4], l[4];
            #pragma unroll
            for (int e = 0; e < 4; ++e) {
                h[e] = f2bf(f[e]);
                l[e] = f2bf(f[e] - bf2f(h[e]));
            }
            xh = make_ushort4(h[0], h[1], h[2], h[3]);
            xl = make_ushort4(l[0], l[1], l[2], l[3]);
        }
        *(ushort4*)&xsh[0][srow][sf4] = xh;
        *(ushort4*)&xsh[1][srow][sf4] = xl;
        __syncthreads();

        bf16x8 xfh[2], xfl[2];
        #pragma unroll
        for (int mt = 0; mt < 2; ++mt) {
            xfh[mt] = *(const bf16x8*)&xsh[0][16*mt + q15][8*g];
            xfl[mt] = *(const bf16x8*)&xsh[1][16*mt + q15][8*g];
        }
        #pragma unroll
        for (int i = 0; i < 3; ++i) {
            int nt = 3*wv + i;
            size_t base = ((size_t)nt*24 + kc)*512 + (size_t)lane*8;
            bf16x8 wfh = *(const bf16x8*)(wfrag + base);
            bf16x8 wfl = *(const bf16x8*)(wfrag + WFRAG_HALF + base);
            #pragma unroll
            for (int mt = 0; mt < 2; ++mt) {
                acc[mt][i] = __builtin_amdgcn_mfma_f32_16x16x32_bf16(xfh[mt], wfh, acc[mt][i], 0, 0, 0);
                acc[mt][i] = __builtin_amdgcn_mfma_f32_16x16x32_bf16(xfl[mt], wfh, acc[mt][i], 0, 0, 0);
                acc[mt][i] = __builtin_amdgcn_mfma_f32_16x16x32_bf16(xfh[mt], wfl, acc[mt][i], 0, 0, 0);
            }
        }
    }

    // epilogue: C col = 16*ntm + q15, rows = row0 + 16mt + 4g + r
    const int b  = row0 >> 11;
    const int t0 = row0 & 2047;
    #pragma unroll
    for (int i = 0; i < 3; ++i) {
        int nt = 3*wv + i, m = nt >> 2, ntm = nt & 3;
        int col = 16*ntm + q15;
        float bb = (m == 0) ? 0.125f*bq[col] : ((m == 1) ? bk[col] : bv[col]);
        #pragma unroll
        for (int mt = 0; mt < 2; ++mt) {
            if (m == 2) {
                ushort4 pk;
                pk.x = f2bf(acc[mt][i][0] + bb);
                pk.y = f2bf(acc[mt][i][1] + bb);
                pk.z = f2bf(acc[mt][i][2] + bb);
                pk.w = f2bf(acc[mt][i][3] + bb);
                *(ushort4*)(vT + ((size_t)b*HD + col)*TT + t0 + 16*mt + 4*g) = pk;
            } else {
                unsigned short* op = (m == 0) ? qo : ko;
                #pragma unroll
                for (int r = 0; r < 4; ++r)
                    op[(size_t)(row0 + 16*mt + 4*g + r)*HD + col] = f2bf(acc[mt][i][r] + bb);
            }
        }
    }
}

// -------- Flash attention: bf16 MFMA, in-block 4-way key split (unchanged) --------
__global__ __launch_bounds__(256) void attn_mfma_kernel(
    const unsigned short* __restrict__ qb_, const unsigned short* __restrict__ kb_,
    const unsigned short* __restrict__ vt_, float* __restrict__ out)
{
    __shared__ unsigned short plds[4][16][40];
    __shared__ float olds[4][16][66];
    __shared__ float mlds[4][16][2];

    const int tid  = threadIdx.x;
    const int wv   = tid >> 6;
    const int lane = tid & 63;
    const int q15  = lane & 15;
    const int g    = lane >> 4;

    const int bx = blockIdx.x;
    const int b  = bx & 3;
    const int qt = (TT/16 - 1) - (bx >> 2);
    const int qbase = qt * 16;
    const int nk = qbase + 16;

    const unsigned short* qp = qb_ + (size_t)b*TT*HD;
    const unsigned short* kp = kb_ + (size_t)b*TT*HD;
    const unsigned short* vp = vt_ + (size_t)b*HD*TT;

    bf16x8 qf[2];
    #pragma unroll
    for (int c = 0; c < 2; ++c)
        qf[c] = *(const bf16x8*)(qp + (size_t)(qbase + q15)*HD + 32*c + 8*g);

    f32x4 accv[4];
    #pragma unroll
    for (int h = 0; h < 4; ++h) accv[h] = (f32x4){0.f, 0.f, 0.f, 0.f};
    float m = -INFINITY, l = 0.f;

    const int ck = ((nk + 127) >> 7) << 5;
    const int kstart = wv * ck;
    const int kend = min(kstart + ck, nk);

    for (int k0 = kstart; k0 < kend; k0 += 32) {
        bf16x8 vf[4];
        #pragma unroll
        for (int h = 0; h < 4; ++h)
            vf[h] = *(const bf16x8*)(vp + (size_t)(16*h + q15)*TT + k0 + 8*g);
        bf16x8 kf[2][2];
        #pragma unroll
        for (int t = 0; t < 2; ++t)
            #pragma unroll
            for (int c = 0; c < 2; ++c)
                kf[t][c] = *(const bf16x8*)(kp + (size_t)(k0 + 16*t + q15)*HD + 32*c + 8*g);

        f32x4 st[2];
        #pragma unroll
        for (int t = 0; t < 2; ++t) {
            f32x4 z = {0.f, 0.f, 0.f, 0.f};
            st[t] = __builtin_amdgcn_mfma_f32_16x16x32_bf16(kf[t][0], qf[0], z, 0, 0, 0);
            st[t] = __builtin_amdgcn_mfma_f32_16x16x32_bf16(kf[t][1], qf[1], st[t], 0, 0, 0);
        }
        if (k0 + 31 > qbase) {
            int qabs = qbase + q15;
            #pragma unroll
            for (int t = 0; t < 2; ++t)
                #pragma unroll
                for (int r = 0; r < 4; ++r)
                    if (k0 + 16*t + 4*g + r > qabs) st[t][r] = -INFINITY;
        }
        float pmax = st[0][0];
        #pragma unroll
        for (int t = 0; t < 2; ++t)
            #pragma unroll
            for (int r = 0; r < 4; ++r) pmax = fmaxf(pmax, st[t][r]);
        pmax = fmaxf(pmax, __shfl_xor(pmax, 16));
        pmax = fmaxf(pmax, __shfl_xor(pmax, 32));
        float mnew = fmaxf(m, pmax);
        float mc = fmaxf(mnew, -1e30f);
        float alpha = __expf(m - mc);
        float p[2][4];
        float psum = 0.f;
        #pragma unroll
        for (int t = 0; t < 2; ++t)
            #pragma unroll
            for (int r = 0; r < 4; ++r) {
                p[t][r] = __expf(st[t][r] - mc);
                psum += p[t][r];
            }
        psum += __shfl_xor(psum, 16);
        psum += __shfl_xor(psum, 32);
        l = l * alpha + psum;
        m = mnew;
        float av[4];
        #pragma unroll
        for (int r = 0; r < 4; ++r) av[r] = __shfl(alpha, 4*g + r);
        #pragma unroll
        for (int h = 0; h < 4; ++h)
            #pragma unroll
            for (int r = 0; r < 4; ++r) accv[h][r] *= av[r];
        #pragma unroll
        for (int t = 0; t < 2; ++t) {
            ushort4 pk;
            pk.x = f2bf(p[t][0]); pk.y = f2bf(p[t][1]);
            pk.z = f2bf(p[t][2]); pk.w = f2bf(p[t][3]);
            *(ushort4*)&plds[wv][q15][16*t + 4*g] = pk;
        }
        bf16x8 pa = *(const bf16x8*)&plds[wv][q15][8*g];
        #pragma unroll
        for (int h = 0; h < 4; ++h)
            accv[h] = __builtin_amdgcn_mfma_f32_16x16x32_bf16(pa, vf[h], accv[h], 0, 0, 0);
    }

    #pragma unroll
    for (int h = 0; h < 4; ++h)
        #pragma unroll
        for (int r = 0; r < 4; ++r)
            olds[wv][4*g + r][16*h + q15] = accv[h][r];
    if (g == 0) { mlds[wv][q15][0] = m; mlds[wv][q15][1] = l; }
    __syncthreads();

    {
        int qq = tid >> 4;
        int c4 = (tid & 15) << 2;
        float mw[4], lw[4];
        #pragma unroll
        for (int w = 0; w < 4; ++w) { mw[w] = mlds[w][qq][0]; lw[w] = mlds[w][qq][1]; }
        float M = fmaxf(fmaxf(mw[0], mw[1]), fmaxf(mw[2], mw[3]));
        float Mc = fmaxf(M, -1e30f);
        float ww[4], ltot = 0.f;
        #pragma unroll
        for (int w = 0; w < 4; ++w) { ww[w] = __expf(mw[w] - Mc); ltot += ww[w]*lw[w]; }
        float invl = 1.f / ltot;
        float4 o;
        #pragma unroll
        for (int e = 0; e < 4; ++e) {
            float s = 0.f;
            #pragma unroll
            for (int w = 0; w < 4; ++w) s += ww[w] * olds[w][qq][c4 + e];
            ((float*)&o)[e] = s * invl;
        }
        *(float4*)(out + ((size_t)b*TT + qbase + qq)*HD + c4) = o;
    }
}

extern "C" void kernel_launch(void* const* d_in, const int* in_sizes, int n_in,
                              void* d_out, int out_size, void* d_ws, size_t ws_size,
                              hipStream_t stream) {
    const float* x  = (const float*)d_in[0];
    const float* Wq = (const float*)d_in[1];
    const float* bq = (const float*)d_in[2];
    const float* Wk = (const float*)d_in[3];
    const float* bk = (const float*)d_in[4];
    const float* Wv = (const float*)d_in[5];
    const float* bv = (const float*)d_in[6];
    float* out = (float*)d_out;

    unsigned short* qbf   = (unsigned short*)d_ws;
    unsigned short* kbf   = qbf + (size_t)NROW*HD;
    unsigned short* vT    = kbf + (size_t)NROW*HD;
    unsigned short* wfrag = vT  + (size_t)NROW*HD;   // 2*147456 elems = 576KB

    wconv_kernel<<<288, 256, 0, stream>>>(Wq, Wk, Wv, wfrag);
    proj_mfma_kernel<<<NROW/32, 256, 0, stream>>>(x, wfrag, bq, bk, bv, qbf, kbf, vT);
    attn_mfma_kernel<<<dim3(TT/16 * BB), 256, 0, stream>>>(qbf, kbf, vT, out);
}

// Round 5
// 50.950 us; speedup vs baseline: 3.0647x; 1.3388x over previous
//
#include <hip/hip_runtime.h>
#include <math.h>

#define BB 4
#define TT 2048
#define DM 768
#define HD 64
#define NROW (BB*TT)   // 8192
#define WFRAG_HALF ((size_t)12*24*512)   // elems per part

typedef __attribute__((ext_vector_type(8))) short bf16x8;
typedef __attribute__((ext_vector_type(4))) float f32x4;

__device__ __forceinline__ unsigned short f2bf(float f) {
    unsigned int u = __float_as_uint(f);
    u += 0x7FFFu + ((u >> 16) & 1u);   // RNE
    return (unsigned short)(u >> 16);
}
__device__ __forceinline__ float bf2f(unsigned short h) {
    return __uint_as_float(((unsigned int)h) << 16);
}

// -------- W -> MFMA-fragment-ordered bf16 hi/lo (LDS transpose, coalesced) --------
// grid 72 = m(3) x kc(24); frag elem: W[32kc+8g+j][16ntm+q15], q-scale folded (m=0).
__global__ __launch_bounds__(256) void wconv_kernel(
    const float* __restrict__ Wq, const float* __restrict__ Wk,
    const float* __restrict__ Wv, unsigned short* __restrict__ wfrag)
{
    __shared__ float ws[32][69];
    const int blk = blockIdx.x;
    const int m = blk / 24, kc = blk % 24;
    const float* Wm = (m == 0) ? Wq : ((m == 1) ? Wk : Wv);
    const float sc = (m == 0) ? 0.125f : 1.0f;
    const int tid = threadIdx.x;
    // coalesced load of 32x64 tile
    {
        int r = tid >> 3, c0 = (tid & 7) * 8;
        *(float4*)&ws[r][c0]     = *(const float4*)(Wm + (size_t)(32*kc + r)*HD + c0);
        *(float4*)&ws[r][c0 + 4] = *(const float4*)(Wm + (size_t)(32*kc + r)*HD + c0 + 4);
    }
    __syncthreads();
    // emit fragments: thread = ntm*64 + lane
    const int ntm = tid >> 6, lane = tid & 63;
    const int q15 = lane & 15, g = lane >> 4;
    const int col = 16*ntm + q15;
    bf16x8 hi, lo;
    #pragma unroll
    for (int j = 0; j < 8; ++j) {
        float w = ws[8*g + j][col] * sc;
        unsigned short h = f2bf(w);
        hi[j] = (short)h;
        lo[j] = (short)f2bf(w - bf2f(h));
    }
    size_t base = ((size_t)((m*4 + ntm)*24 + kc))*512 + (size_t)lane*8;
    *(bf16x8*)(wfrag + base) = hi;
    *(bf16x8*)(wfrag + WFRAG_HALF + base) = lo;
}

// -------- QKV projection via MFMA: BK=128, dbuf LDS, 8 waves --------
// grid 256 x 512thr. Wave w: mt = w&1 (row half), nt = 3*(w>>1)+i, i=0..2.
__global__ __launch_bounds__(512) void proj_mfma_kernel(
    const float* __restrict__ x, const unsigned short* __restrict__ wfrag,
    const float* __restrict__ bq, const float* __restrict__ bk,
    const float* __restrict__ bv,
    unsigned short* __restrict__ qo, unsigned short* __restrict__ ko,
    unsigned short* __restrict__ vT)
{
    __shared__ unsigned short xsh[2][2][32][132];   // [buf][hi/lo][row][k]
    const int tid  = threadIdx.x;
    const int wv   = tid >> 6;
    const int lane = tid & 63;
    const int q15  = lane & 15;
    const int g    = lane >> 4;
    const int row0 = blockIdx.x * 32;
    const int mt   = wv & 1;
    const int nt0  = 3 * (wv >> 1);
    const int xrow = 16*mt + q15;

    // staging coords: 32 rows x 128 cols, 8 floats/thread
    const int srow = tid >> 4;
    const int sc0  = (tid & 15) * 8;
    const float* xrp = x + (size_t)(row0 + srow)*DM + sc0;

    f32x4 acc[3];
    #pragma unroll
    for (int i = 0; i < 3; ++i) acc[i] = (f32x4){0.f, 0.f, 0.f, 0.f};

    // prologue: stage chunk 0 into buf 0
    {
        float4 xa = *(const float4*)(xrp);
        float4 xb = *(const float4*)(xrp + 4);
        bf16x8 hi, lo;
        float f[8] = {xa.x, xa.y, xa.z, xa.w, xb.x, xb.y, xb.z, xb.w};
        #pragma unroll
        for (int e = 0; e < 8; ++e) {
            unsigned short h = f2bf(f[e]);
            hi[e] = (short)h;
            lo[e] = (short)f2bf(f[e] - bf2f(h));
        }
        *(bf16x8*)&xsh[0][0][srow][sc0] = hi;
        *(bf16x8*)&xsh[0][1][srow][sc0] = lo;
    }
    __syncthreads();

    for (int t = 0; t < 6; ++t) {
        const int buf = t & 1;
        // prefetch next x chunk (issue early; consumed after compute)
        float4 xa, xb;
        if (t < 5) {
            xa = *(const float4*)(xrp + (t+1)*128);
            xb = *(const float4*)(xrp + (t+1)*128 + 4);
        }
        #pragma unroll
        for (int sub = 0; sub < 4; ++sub) {
            const int kcg = t*4 + sub;
            bf16x8 xfh = *(const bf16x8*)&xsh[buf][0][xrow][32*sub + 8*g];
            bf16x8 xfl = *(const bf16x8*)&xsh[buf][1][xrow][32*sub + 8*g];
            #pragma unroll
            for (int i = 0; i < 3; ++i) {
                const unsigned short* wp = wfrag + ((size_t)((nt0 + i)*24 + kcg))*512 + (size_t)lane*8;
                bf16x8 wh = *(const bf16x8*)wp;
                bf16x8 wl = *(const bf16x8*)(wp + WFRAG_HALF);
                acc[i] = __builtin_amdgcn_mfma_f32_16x16x32_bf16(xfh, wh, acc[i], 0, 0, 0);
                acc[i] = __builtin_amdgcn_mfma_f32_16x16x32_bf16(xfl, wh, acc[i], 0, 0, 0);
                acc[i] = __builtin_amdgcn_mfma_f32_16x16x32_bf16(xfh, wl, acc[i], 0, 0, 0);
            }
        }
        if (t < 5) {
            bf16x8 hi, lo;
            float f[8] = {xa.x, xa.y, xa.z, xa.w, xb.x, xb.y, xb.z, xb.w};
            #pragma unroll
            for (int e = 0; e < 8; ++e) {
                unsigned short h = f2bf(f[e]);
                hi[e] = (short)h;
                lo[e] = (short)f2bf(f[e] - bf2f(h));
            }
            *(bf16x8*)&xsh[buf^1][0][srow][sc0] = hi;
            *(bf16x8*)&xsh[buf^1][1][srow][sc0] = lo;
            __syncthreads();
        }
    }

    // epilogue: C col = 16*ntm + q15, rows = row0 + 16*mt + 4g + r
    const int b  = row0 >> 11;
    const int t0 = row0 & 2047;
    #pragma unroll
    for (int i = 0; i < 3; ++i) {
        int nt = nt0 + i, m = nt >> 2, ntm = nt & 3;
        int col = 16*ntm + q15;
        float bb = (m == 0) ? 0.125f*bq[col] : ((m == 1) ? bk[col] : bv[col]);
        if (m == 2) {
            ushort4 pk;
            pk.x = f2bf(acc[i][0] + bb);
            pk.y = f2bf(acc[i][1] + bb);
            pk.z = f2bf(acc[i][2] + bb);
            pk.w = f2bf(acc[i][3] + bb);
            *(ushort4*)(vT + ((size_t)b*HD + col)*TT + t0 + 16*mt + 4*g) = pk;
        } else {
            unsigned short* op = (m == 0) ? qo : ko;
            #pragma unroll
            for (int r = 0; r < 4; ++r)
                op[(size_t)(row0 + 16*mt + 4*g + r)*HD + col] = f2bf(acc[i][r] + bb);
        }
    }
}

// -------- Flash attention: bf16 MFMA, in-block 4-way key split (unchanged) --------
__global__ __launch_bounds__(256) void attn_mfma_kernel(
    const unsigned short* __restrict__ qb_, const unsigned short* __restrict__ kb_,
    const unsigned short* __restrict__ vt_, float* __restrict__ out)
{
    __shared__ unsigned short plds[4][16][40];
    __shared__ float olds[4][16][66];
    __shared__ float mlds[4][16][2];

    const int tid  = threadIdx.x;
    const int wv   = tid >> 6;
    const int lane = tid & 63;
    const int q15  = lane & 15;
    const int g    = lane >> 4;

    const int bx = blockIdx.x;
    const int b  = bx & 3;
    const int qt = (TT/16 - 1) - (bx >> 2);
    const int qbase = qt * 16;
    const int nk = qbase + 16;

    const unsigned short* qp = qb_ + (size_t)b*TT*HD;
    const unsigned short* kp = kb_ + (size_t)b*TT*HD;
    const unsigned short* vp = vt_ + (size_t)b*HD*TT;

    bf16x8 qf[2];
    #pragma unroll
    for (int c = 0; c < 2; ++c)
        qf[c] = *(const bf16x8*)(qp + (size_t)(qbase + q15)*HD + 32*c + 8*g);

    f32x4 accv[4];
    #pragma unroll
    for (int h = 0; h < 4; ++h) accv[h] = (f32x4){0.f, 0.f, 0.f, 0.f};
    float m = -INFINITY, l = 0.f;

    const int ck = ((nk + 127) >> 7) << 5;
    const int kstart = wv * ck;
    const int kend = min(kstart + ck, nk);

    for (int k0 = kstart; k0 < kend; k0 += 32) {
        bf16x8 vf[4];
        #pragma unroll
        for (int h = 0; h < 4; ++h)
            vf[h] = *(const bf16x8*)(vp + (size_t)(16*h + q15)*TT + k0 + 8*g);
        bf16x8 kf[2][2];
        #pragma unroll
        for (int t = 0; t < 2; ++t)
            #pragma unroll
            for (int c = 0; c < 2; ++c)
                kf[t][c] = *(const bf16x8*)(kp + (size_t)(k0 + 16*t + q15)*HD + 32*c + 8*g);

        f32x4 st[2];
        #pragma unroll
        for (int t = 0; t < 2; ++t) {
            f32x4 z = {0.f, 0.f, 0.f, 0.f};
            st[t] = __builtin_amdgcn_mfma_f32_16x16x32_bf16(kf[t][0], qf[0], z, 0, 0, 0);
            st[t] = __builtin_amdgcn_mfma_f32_16x16x32_bf16(kf[t][1], qf[1], st[t], 0, 0, 0);
        }
        if (k0 + 31 > qbase) {
            int qabs = qbase + q15;
            #pragma unroll
            for (int t = 0; t < 2; ++t)
                #pragma unroll
                for (int r = 0; r < 4; ++r)
                    if (k0 + 16*t + 4*g + r > qabs) st[t][r] = -INFINITY;
        }
        float pmax = st[0][0];
        #pragma unroll
        for (int t = 0; t < 2; ++t)
            #pragma unroll
            for (int r = 0; r < 4; ++r) pmax = fmaxf(pmax, st[t][r]);
        pmax = fmaxf(pmax, __shfl_xor(pmax, 16));
        pmax = fmaxf(pmax, __shfl_xor(pmax, 32));
        float mnew = fmaxf(m, pmax);
        float mc = fmaxf(mnew, -1e30f);
        float alpha = __expf(m - mc);
        float p[2][4];
        float psum = 0.f;
        #pragma unroll
        for (int t = 0; t < 2; ++t)
            #pragma unroll
            for (int r = 0; r < 4; ++r) {
                p[t][r] = __expf(st[t][r] - mc);
                psum += p[t][r];
            }
        psum += __shfl_xor(psum, 16);
        psum += __shfl_xor(psum, 32);
        l = l * alpha + psum;
        m = mnew;
        float av[4];
        #pragma unroll
        for (int r = 0; r < 4; ++r) av[r] = __shfl(alpha, 4*g + r);
        #pragma unroll
        for (int h = 0; h < 4; ++h)
            #pragma unroll
            for (int r = 0; r < 4; ++r) accv[h][r] *= av[r];
        #pragma unroll
        for (int t = 0; t < 2; ++t) {
            ushort4 pk;
            pk.x = f2bf(p[t][0]); pk.y = f2bf(p[t][1]);
            pk.z = f2bf(p[t][2]); pk.w = f2bf(p[t][3]);
            *(ushort4*)&plds[wv][q15][16*t + 4*g] = pk;
        }
        bf16x8 pa = *(const bf16x8*)&plds[wv][q15][8*g];
        #pragma unroll
        for (int h = 0; h < 4; ++h)
            accv[h] = __builtin_amdgcn_mfma_f32_16x16x32_bf16(pa, vf[h], accv[h], 0, 0, 0);
    }

    #pragma unroll
    for (int h = 0; h < 4; ++h)
        #pragma unroll
        for (int r = 0; r < 4; ++r)
            olds[wv][4*g + r][16*h + q15] = accv[h][r];
    if (g == 0) { mlds[wv][q15][0] = m; mlds[wv][q15][1] = l; }
    __syncthreads();

    {
        int qq = tid >> 4;
        int c4 = (tid & 15) << 2;
        float mw[4], lw[4];
        #pragma unroll
        for (int w = 0; w < 4; ++w) { mw[w] = mlds[w][qq][0]; lw[w] = mlds[w][qq][1]; }
        float M = fmaxf(fmaxf(mw[0], mw[1]), fmaxf(mw[2], mw[3]));
        float Mc = fmaxf(M, -1e30f);
        float ww[4], ltot = 0.f;
        #pragma unroll
        for (int w = 0; w < 4; ++w) { ww[w] = __expf(mw[w] - Mc); ltot += ww[w]*lw[w]; }
        float invl = 1.f / ltot;
        float4 o;
        #pragma unroll
        for (int e = 0; e < 4; ++e) {
            float s = 0.f;
            #pragma unroll
            for (int w = 0; w < 4; ++w) s += ww[w] * olds[w][qq][c4 + e];
            ((float*)&o)[e] = s * invl;
        }
        *(float4*)(out + ((size_t)b*TT + qbase + qq)*HD + c4) = o;
    }
}

extern "C" void kernel_launch(void* const* d_in, const int* in_sizes, int n_in,
                              void* d_out, int out_size, void* d_ws, size_t ws_size,
                              hipStream_t stream) {
    const float* x  = (const float*)d_in[0];
    const float* Wq = (const float*)d_in[1];
    const float* bq = (const float*)d_in[2];
    const float* Wk = (const float*)d_in[3];
    const float* bk = (const float*)d_in[4];
    const float* Wv = (const float*)d_in[5];
    const float* bv = (const float*)d_in[6];
    float* out = (float*)d_out;

    unsigned short* qbf   = (unsigned short*)d_ws;
    unsigned short* kbf   = qbf + (size_t)NROW*HD;
    unsigned short* vT    = kbf + (size_t)NROW*HD;
    unsigned short* wfrag = vT  + (size_t)NROW*HD;   // 2*147456 elems = 576KB

    wconv_kernel<<<72, 256, 0, stream>>>(Wq, Wk, Wv, wfrag);
    proj_mfma_kernel<<<NROW/32, 512, 0, stream>>>(x, wfrag, bq, bk, bv, qbf, kbf, vT);
    attn_mfma_kernel<<<dim3(TT/16 * BB), 256, 0, stream>>>(qbf, kbf, vT, out);
}